// Round 1
// baseline (239.820 us; speedup 1.0000x reference)
//
#include <hip/hip_runtime.h>
#include <hip/hip_bf16.h>

#define MODELS 64
#define BATCH 64
#define IN_DIM 512
#define UNITS 512
#define NCOLS (4 * UNITS)  // 2048

typedef __attribute__((ext_vector_type(8))) short short8;
typedef __attribute__((ext_vector_type(4))) float f32x4;

static __device__ __forceinline__ short f2bf(float f) {
    return __builtin_bit_cast(short, __float2bfloat16(f));
}

static __device__ __forceinline__ float sigmoidf_(float x) {
    return 1.0f / (1.0f + __expf(-x));
}

static __device__ __forceinline__ float tanhf_(float x) {
    float e = __expf(-2.0f * fabsf(x));
    float r = (1.0f - e) / (1.0f + e);
    return copysignf(r, x);
}

__global__ __launch_bounds__(256, 2) void lstm_fused_kernel(
    const float* __restrict__ inputs,   // [M, B, IN_DIM]
    const float* __restrict__ h_tm1,    // [M, B, UNITS]
    const float* __restrict__ c_tm1,    // [M, B, UNITS]
    const float* __restrict__ kernel,   // [M, IN_DIM, 4U]
    const float* __restrict__ rkernel,  // [M, UNITS, 4U]
    const float* __restrict__ bias,     // [M, 1, 4U]
    float* __restrict__ out)            // h | h | c, each [M, B, UNITS]
{
    const int bid = blockIdx.x;
    const int m = bid >> 3;             // model
    const int u0 = (bid & 7) * 64;      // unit tile base
    const int tid = threadIdx.x;
    const int wave = tid >> 6;
    const int lane = tid & 63;
    const int col16 = lane & 15;        // fragment column (and A row)
    const int kg8 = (lane >> 4) * 8;    // k offset inside a 32-wide K step
    const int bcol = u0 + wave * 16 + col16;  // unit column this lane owns

    f32x4 acc[4][4];                    // [mrep][gate]
#pragma unroll
    for (int i = 0; i < 4; ++i)
#pragma unroll
        for (int g = 0; g < 4; ++g) acc[i][g] = (f32x4){0.f, 0.f, 0.f, 0.f};

    const float* actbase[2] = { inputs + (size_t)m * BATCH * IN_DIM,
                                h_tm1 + (size_t)m * BATCH * UNITS };
    const float* wgtbase[2] = { kernel + (size_t)m * IN_DIM * NCOLS,
                                rkernel + (size_t)m * UNITS * NCOLS };

#pragma unroll
    for (int pass = 0; pass < 2; ++pass) {
        const float* act = actbase[pass];
        const float* wp = wgtbase[pass] + bcol;
        for (int k0 = 0; k0 < 512; k0 += 32) {
            // ---- A fragments: act[row = mr*16 + col16][k0 + kg8 + 0..7] ----
            short8 af[4];
#pragma unroll
            for (int mr = 0; mr < 4; ++mr) {
                const float* ap = act + (size_t)(mr * 16 + col16) * IN_DIM + k0 + kg8;
                f32x4 a0 = *(const f32x4*)ap;
                f32x4 a1 = *(const f32x4*)(ap + 4);
                short8 v;
                v[0] = f2bf(a0[0]); v[1] = f2bf(a0[1]); v[2] = f2bf(a0[2]); v[3] = f2bf(a0[3]);
                v[4] = f2bf(a1[0]); v[5] = f2bf(a1[1]); v[6] = f2bf(a1[2]); v[7] = f2bf(a1[3]);
                af[mr] = v;
            }
            // ---- B fragments: w[k0 + kg8 + i][gate*512 + bcol], i = 0..7 ----
            float b0[8], b1[8], b2[8], b3[8];
            {
                const float* wr = wp + (size_t)(k0 + kg8) * NCOLS;
#pragma unroll
                for (int i = 0; i < 8; ++i) {
                    b0[i] = wr[0];
                    b1[i] = wr[512];
                    b2[i] = wr[1024];
                    b3[i] = wr[1536];
                    wr += NCOLS;
                }
            }
            short8 bf[4];
#pragma unroll
            for (int i = 0; i < 8; ++i) {
                bf[0][i] = f2bf(b0[i]);
                bf[1][i] = f2bf(b1[i]);
                bf[2][i] = f2bf(b2[i]);
                bf[3][i] = f2bf(b3[i]);
            }
            // ---- MFMA ----
#pragma unroll
            for (int mr = 0; mr < 4; ++mr)
#pragma unroll
                for (int g = 0; g < 4; ++g)
                    acc[mr][g] = __builtin_amdgcn_mfma_f32_16x16x32_bf16(
                        af[mr], bf[g], acc[mr][g], 0, 0, 0);
        }
    }

    // ---- fused gate epilogue, fully in-register ----
    const float* bp = bias + (size_t)m * NCOLS;
    const float bi = bp[0 * 512 + bcol];
    const float bff = bp[1 * 512 + bcol];
    const float bcc = bp[2 * 512 + bcol];
    const float bo = bp[3 * 512 + bcol];

    const size_t mbase = (size_t)m * BATCH * UNITS;
    const float* cprev = c_tm1 + mbase;
    float* hout0 = out;
    float* hout1 = out + (size_t)MODELS * BATCH * UNITS;
    float* cout = out + 2 * (size_t)MODELS * BATCH * UNITS;

    const int rowoff = (lane >> 4) * 4;
#pragma unroll
    for (int mr = 0; mr < 4; ++mr) {
#pragma unroll
        for (int r = 0; r < 4; ++r) {
            const int b = mr * 16 + rowoff + r;  // batch row (D row layout)
            const float z0 = acc[mr][0][r] + bi;
            const float z1 = acc[mr][1][r] + bff;
            const float z2 = acc[mr][2][r] + bcc;
            const float z3 = acc[mr][3][r] + bo;
            const float ig = sigmoidf_(z0);
            const float fg = sigmoidf_(z1);
            const float cand = tanhf_(z2);
            const float og = sigmoidf_(z3);
            const size_t idx = (size_t)b * UNITS + bcol;
            const float c = fg * cprev[idx] + ig * cand;
            const float h = og * tanhf_(c);
            hout0[mbase + idx] = h;
            hout1[mbase + idx] = h;
            cout[mbase + idx] = c;
        }
    }
}

extern "C" void kernel_launch(void* const* d_in, const int* in_sizes, int n_in,
                              void* d_out, int out_size, void* d_ws, size_t ws_size,
                              hipStream_t stream) {
    const float* inputs = (const float*)d_in[0];
    const float* h_tm1 = (const float*)d_in[1];
    const float* c_tm1 = (const float*)d_in[2];
    const float* kernel = (const float*)d_in[3];
    const float* rkernel = (const float*)d_in[4];
    const float* bias = (const float*)d_in[5];
    float* out = (float*)d_out;

    dim3 grid(MODELS * 8);   // 64 models x 8 unit tiles of 64
    dim3 block(256);         // 4 waves; wave w owns a 16-unit slice, all 4 gates
    hipLaunchKernelGGL(lstm_fused_kernel, grid, block, 0, stream,
                       inputs, h_tm1, c_tm1, kernel, rkernel, bias, out);
}

// Round 2
// 200.546 us; speedup vs baseline: 1.1958x; 1.1958x over previous
//
#include <hip/hip_runtime.h>
#include <hip/hip_bf16.h>

#define MODELS 64
#define BATCH 64
#define IN_DIM 512
#define UNITS 512
#define NCOLS (4 * UNITS)  // 2048
// Packed-A geometry: per tensor, [M][16 ksteps][4 kgroups][64 rows] granules of 8 bf16 (16 B)
#define GRAN_PER_TENSOR (MODELS * 16 * 4 * 64)  // 262144 granules = 4 MB/tensor

typedef __attribute__((ext_vector_type(8))) short short8;
typedef __attribute__((ext_vector_type(4))) float f32x4;

static __device__ __forceinline__ short f2bf(float f) {
    return __builtin_bit_cast(short, __float2bfloat16(f));
}
static __device__ __forceinline__ float sigmoidf_(float x) {
    return 1.0f / (1.0f + __expf(-x));
}
static __device__ __forceinline__ float tanhf_(float x) {
    float e = __expf(-2.0f * fabsf(x));
    float r = (1.0f - e) / (1.0f + e);
    return copysignf(r, x);
}

// Re-layout inputs & h_tm1 (f32) into bf16 MFMA-A-fragment order:
// P[tensor][m][ks][kg][row] granule = act[m][row][ks*32 + kg*8 .. +8]
__global__ __launch_bounds__(256) void prepack_A_kernel(
    const float* __restrict__ x, const float* __restrict__ h,
    short8* __restrict__ P)
{
    const int t = blockIdx.x * 256 + threadIdx.x;   // [0, 2*262144)
    const int tensor = t >> 18;
    const int r = t & (GRAN_PER_TENSOR - 1);
    const int kg = r & 3;            // adjacent threads share a 128B source line
    const int row = (r >> 2) & 63;
    const int ks = (r >> 8) & 15;
    const int m = r >> 12;
    const float* src = (tensor ? h : x) + ((size_t)(m * 64 + row) * 512 + ks * 32 + kg * 8);
    f32x4 a0 = *(const f32x4*)src;
    f32x4 a1 = *(const f32x4*)(src + 4);
    short8 v;
    v[0] = f2bf(a0[0]); v[1] = f2bf(a0[1]); v[2] = f2bf(a0[2]); v[3] = f2bf(a0[3]);
    v[4] = f2bf(a1[0]); v[5] = f2bf(a1[1]); v[6] = f2bf(a1[2]); v[7] = f2bf(a1[3]);
    P[(size_t)tensor * GRAN_PER_TENSOR + (size_t)((m * 16 + ks) * 4 + kg) * 64 + row] = v;
}

template <bool PACKED>
__global__ __launch_bounds__(256, 2) void lstm_main_kernel(
    const float* __restrict__ inputs,   // [M, B, IN_DIM]
    const float* __restrict__ h_tm1,    // [M, B, UNITS]
    const float* __restrict__ c_tm1,    // [M, B, UNITS]
    const float* __restrict__ kernel,   // [M, IN_DIM, 4U]
    const float* __restrict__ rkernel,  // [M, UNITS, 4U]
    const float* __restrict__ bias,     // [M, 1, 4U]
    const short8* __restrict__ Pa,      // packed A (2 tensors) or null
    float* __restrict__ out)            // h | h | c
{
    const int bid = blockIdx.x;
    const int m = bid >> 3;
    const int u0 = (bid & 7) * 64;
    const int lane = threadIdx.x & 63;
    const int wave = threadIdx.x >> 6;
    const int col16 = lane & 15;
    const int kq = lane >> 4;          // k-group within a 32-wide K step
    const int bcol = u0 + wave * 16 + col16;

    f32x4 acc[4][4];                   // [mrep][gate]
#pragma unroll
    for (int i = 0; i < 4; ++i)
#pragma unroll
        for (int g = 0; g < 4; ++g) acc[i][g] = (f32x4){0.f, 0.f, 0.f, 0.f};

    const float* actbase[2] = { inputs + (size_t)m * BATCH * IN_DIM,
                                h_tm1 + (size_t)m * BATCH * UNITS };
    const float* wgtbase[2] = { kernel + (size_t)m * IN_DIM * NCOLS,
                                rkernel + (size_t)m * UNITS * NCOLS };

#pragma unroll
    for (int pass = 0; pass < 2; ++pass) {
        const float* wp = wgtbase[pass] + bcol;
        const short8* pp = PACKED
            ? Pa + (size_t)pass * GRAN_PER_TENSOR + (size_t)m * (16 * 4 * 64)
            : nullptr;
        const float* act = actbase[pass];
#pragma unroll 2
        for (int ks = 0; ks < 16; ++ks) {
            // ---- B: w[ks*32 + kq*8 + i][gate*512 + bcol], 4x64B segments/instr ----
            float b0[8], b1[8], b2[8], b3[8];
            {
                const float* wr = wp + (size_t)(ks * 32 + kq * 8) * NCOLS;
#pragma unroll
                for (int i = 0; i < 8; ++i) {
                    b0[i] = wr[0];
                    b1[i] = wr[512];
                    b2[i] = wr[1024];
                    b3[i] = wr[1536];
                    wr += NCOLS;
                }
            }
            // ---- A fragments ----
            short8 af[4];
            if (PACKED) {
                const short8* pk = pp + (size_t)(ks * 4 + kq) * 64 + col16;
                af[0] = pk[0];
                af[1] = pk[16];
                af[2] = pk[32];
                af[3] = pk[48];
            } else {
#pragma unroll
                for (int mr = 0; mr < 4; ++mr) {
                    const float* ap = act + (size_t)(mr * 16 + col16) * 512 + ks * 32 + kq * 8;
                    f32x4 a0 = *(const f32x4*)ap;
                    f32x4 a1 = *(const f32x4*)(ap + 4);
                    short8 v;
                    v[0] = f2bf(a0[0]); v[1] = f2bf(a0[1]); v[2] = f2bf(a0[2]); v[3] = f2bf(a0[3]);
                    v[4] = f2bf(a1[0]); v[5] = f2bf(a1[1]); v[6] = f2bf(a1[2]); v[7] = f2bf(a1[3]);
                    af[mr] = v;
                }
            }
            // ---- convert B to bf16 fragments ----
            short8 bfr[4];
#pragma unroll
            for (int i = 0; i < 8; ++i) {
                bfr[0][i] = f2bf(b0[i]);
                bfr[1][i] = f2bf(b1[i]);
                bfr[2][i] = f2bf(b2[i]);
                bfr[3][i] = f2bf(b3[i]);
            }
            // ---- MFMA ----
#pragma unroll
            for (int mr = 0; mr < 4; ++mr)
#pragma unroll
                for (int g = 0; g < 4; ++g)
                    acc[mr][g] = __builtin_amdgcn_mfma_f32_16x16x32_bf16(
                        af[mr], bfr[g], acc[mr][g], 0, 0, 0);
        }
    }

    // ---- fused gate epilogue ----
    const float* bp = bias + (size_t)m * NCOLS;
    const float bi = bp[0 * 512 + bcol];
    const float bff = bp[1 * 512 + bcol];
    const float bcc = bp[2 * 512 + bcol];
    const float bo = bp[3 * 512 + bcol];

    const size_t mbase = (size_t)m * BATCH * UNITS;
    const float* cprev = c_tm1 + mbase;
    float* hout0 = out;
    float* hout1 = out + (size_t)MODELS * BATCH * UNITS;
    float* cout = out + 2 * (size_t)MODELS * BATCH * UNITS;

    const int rowoff = kq * 4;
#pragma unroll
    for (int mr = 0; mr < 4; ++mr) {
#pragma unroll
        for (int r = 0; r < 4; ++r) {
            const int b = mr * 16 + rowoff + r;
            const float z0 = acc[mr][0][r] + bi;
            const float z1 = acc[mr][1][r] + bff;
            const float z2 = acc[mr][2][r] + bcc;
            const float z3 = acc[mr][3][r] + bo;
            const float ig = sigmoidf_(z0);
            const float fg = sigmoidf_(z1);
            const float cand = tanhf_(z2);
            const float og = sigmoidf_(z3);
            const size_t idx = (size_t)b * UNITS + bcol;
            const float c = fg * cprev[idx] + ig * cand;
            const float hh = og * tanhf_(c);
            hout0[mbase + idx] = hh;
            hout1[mbase + idx] = hh;
            cout[mbase + idx] = c;
        }
    }
}

extern "C" void kernel_launch(void* const* d_in, const int* in_sizes, int n_in,
                              void* d_out, int out_size, void* d_ws, size_t ws_size,
                              hipStream_t stream) {
    const float* inputs = (const float*)d_in[0];
    const float* h_tm1 = (const float*)d_in[1];
    const float* c_tm1 = (const float*)d_in[2];
    const float* kernel = (const float*)d_in[3];
    const float* rkernel = (const float*)d_in[4];
    const float* bias = (const float*)d_in[5];
    float* out = (float*)d_out;

    const size_t need = (size_t)2 * GRAN_PER_TENSOR * sizeof(short8);  // 8 MB
    if (ws_size >= need) {
        short8* P = (short8*)d_ws;
        hipLaunchKernelGGL(prepack_A_kernel, dim3(2 * GRAN_PER_TENSOR / 256), dim3(256),
                           0, stream, inputs, h_tm1, P);
        hipLaunchKernelGGL((lstm_main_kernel<true>), dim3(MODELS * 8), dim3(256), 0, stream,
                           inputs, h_tm1, c_tm1, kernel, rkernel, bias, P, out);
    } else {
        hipLaunchKernelGGL((lstm_main_kernel<false>), dim3(MODELS * 8), dim3(256), 0, stream,
                           inputs, h_tm1, c_tm1, kernel, rkernel, bias, nullptr, out);
    }
}

// Round 3
// 194.896 us; speedup vs baseline: 1.2305x; 1.0290x over previous
//
#include <hip/hip_runtime.h>
#include <hip/hip_bf16.h>

#define MODELS 64
#define BATCH 64
#define IN_DIM 512
#define UNITS 512
#define NCOLS (4 * UNITS)  // 2048
// Packed-A geometry: per tensor, [M][16 ksteps][4 kgroups][64 rows] granules of 8 bf16 (16 B)
#define GRAN_PER_TENSOR (MODELS * 16 * 4 * 64)  // 262144 granules = 4 MB/tensor

typedef __attribute__((ext_vector_type(8))) short short8;
typedef __attribute__((ext_vector_type(4))) float f32x4;

static __device__ __forceinline__ short f2bf(float f) {
    return __builtin_bit_cast(short, __float2bfloat16(f));
}
static __device__ __forceinline__ float sigmoidf_(float x) {
    return 1.0f / (1.0f + __expf(-x));
}
static __device__ __forceinline__ float tanhf_(float x) {
    float e = __expf(-2.0f * fabsf(x));
    float r = (1.0f - e) / (1.0f + e);
    return copysignf(r, x);
}

// Re-layout inputs & h_tm1 (f32) into bf16 MFMA-A-fragment order:
// P[tensor][m][ks][kg][row] granule = act[m][row][ks*32 + kg*8 .. +8]
__global__ __launch_bounds__(256) void prepack_A_kernel(
    const float* __restrict__ x, const float* __restrict__ h,
    short8* __restrict__ P)
{
    const int t = blockIdx.x * 256 + threadIdx.x;   // [0, 2*262144)
    const int tensor = t >> 18;
    const int r = t & (GRAN_PER_TENSOR - 1);
    const int kg = r & 3;            // adjacent threads share a 128B source line
    const int row = (r >> 2) & 63;
    const int ks = (r >> 8) & 15;
    const int m = r >> 12;
    const float* src = (tensor ? h : x) + ((size_t)(m * 64 + row) * 512 + ks * 32 + kg * 8);
    f32x4 a0 = *(const f32x4*)src;
    f32x4 a1 = *(const f32x4*)(src + 4);
    short8 v;
    v[0] = f2bf(a0[0]); v[1] = f2bf(a0[1]); v[2] = f2bf(a0[2]); v[3] = f2bf(a0[3]);
    v[4] = f2bf(a1[0]); v[5] = f2bf(a1[1]); v[6] = f2bf(a1[2]); v[7] = f2bf(a1[3]);
    P[(size_t)tensor * GRAN_PER_TENSOR + (size_t)((m * 16 + ks) * 4 + kg) * 64 + row] = v;
}

// Grid: 1024 blocks. bid -> (tile t, batch-half) such that the two halves of a
// tile are 8 apart in bid => same XCD (round-robin %8) => twin weight reads hit L2.
template <bool PACKED>
__global__ __launch_bounds__(256, 4) void lstm_main_kernel(
    const float* __restrict__ inputs,   // [M, B, IN_DIM]
    const float* __restrict__ h_tm1,    // [M, B, UNITS]
    const float* __restrict__ c_tm1,    // [M, B, UNITS]
    const float* __restrict__ kernel,   // [M, IN_DIM, 4U]
    const float* __restrict__ rkernel,  // [M, UNITS, 4U]
    const float* __restrict__ bias,     // [M, 1, 4U]
    const short8* __restrict__ Pa,      // packed A (2 tensors) or null
    float* __restrict__ out)            // h | h | c
{
    const int bid = blockIdx.x;
    const int xcd = bid & 7;
    const int half = (bid >> 3) & 1;
    const int t = (bid >> 4) * 8 + xcd;     // logical tile [0, 512)
    const int m = t >> 3;
    const int u0 = (t & 7) * 64;
    const int b0 = half * 32;               // batch-row base

    const int lane = threadIdx.x & 63;
    const int wave = threadIdx.x >> 6;
    const int col16 = lane & 15;
    const int kq = lane >> 4;               // k-group within a 32-wide K step
    const int bcol = u0 + wave * 16 + col16;

    f32x4 acc[2][4];                        // [mrep][gate]
#pragma unroll
    for (int i = 0; i < 2; ++i)
#pragma unroll
        for (int g = 0; g < 4; ++g) acc[i][g] = (f32x4){0.f, 0.f, 0.f, 0.f};

    const float* actbase[2] = { inputs + (size_t)m * BATCH * IN_DIM,
                                h_tm1 + (size_t)m * BATCH * UNITS };
    const float* wgtbase[2] = { kernel + (size_t)m * IN_DIM * NCOLS,
                                rkernel + (size_t)m * UNITS * NCOLS };

#pragma unroll
    for (int pass = 0; pass < 2; ++pass) {
        const float* wp = wgtbase[pass] + bcol;
        const short8* pp = PACKED
            ? Pa + (size_t)pass * GRAN_PER_TENSOR + (size_t)m * (16 * 4 * 64)
            : nullptr;
        const float* act = actbase[pass];
#pragma unroll 2
        for (int ks = 0; ks < 16; ++ks) {
            // ---- B: w[ks*32 + kq*8 + i][gate*512 + bcol] ----
            const float* wr0 = wp + (size_t)(ks * 32 + kq * 8) * NCOLS;
            const float* wr1 = wr0 + 512;
            const float* wr2 = wr0 + 1024;
            const float* wr3 = wr0 + 1536;
            float b0a[8], b1a[8], b2a[8], b3a[8];
#pragma unroll
            for (int i = 0; i < 8; ++i) {
                b0a[i] = wr0[(size_t)i * NCOLS];
                b1a[i] = wr1[(size_t)i * NCOLS];
                b2a[i] = wr2[(size_t)i * NCOLS];
                b3a[i] = wr3[(size_t)i * NCOLS];
            }
            // ---- A fragments (2 mreps of 16 batch rows at b0) ----
            short8 af[2];
            if (PACKED) {
                const short8* pk = pp + (size_t)(ks * 4 + kq) * 64 + b0 + col16;
                af[0] = pk[0];
                af[1] = pk[16];
            } else {
#pragma unroll
                for (int mr = 0; mr < 2; ++mr) {
                    const float* ap = act + (size_t)(b0 + mr * 16 + col16) * 512 + ks * 32 + kq * 8;
                    f32x4 a0 = *(const f32x4*)ap;
                    f32x4 a1 = *(const f32x4*)(ap + 4);
                    short8 v;
                    v[0] = f2bf(a0[0]); v[1] = f2bf(a0[1]); v[2] = f2bf(a0[2]); v[3] = f2bf(a0[3]);
                    v[4] = f2bf(a1[0]); v[5] = f2bf(a1[1]); v[6] = f2bf(a1[2]); v[7] = f2bf(a1[3]);
                    af[mr] = v;
                }
            }
            // ---- convert B to bf16 fragments ----
            short8 bfr[4];
#pragma unroll
            for (int i = 0; i < 8; ++i) {
                bfr[0][i] = f2bf(b0a[i]);
                bfr[1][i] = f2bf(b1a[i]);
                bfr[2][i] = f2bf(b2a[i]);
                bfr[3][i] = f2bf(b3a[i]);
            }
            // ---- MFMA ----
#pragma unroll
            for (int mr = 0; mr < 2; ++mr)
#pragma unroll
                for (int g = 0; g < 4; ++g)
                    acc[mr][g] = __builtin_amdgcn_mfma_f32_16x16x32_bf16(
                        af[mr], bfr[g], acc[mr][g], 0, 0, 0);
        }
    }

    // ---- fused gate epilogue ----
    const float* bp = bias + (size_t)m * NCOLS;
    const float bi = bp[0 * 512 + bcol];
    const float bff = bp[1 * 512 + bcol];
    const float bcc = bp[2 * 512 + bcol];
    const float bo = bp[3 * 512 + bcol];

    const size_t mbase = (size_t)m * BATCH * UNITS;
    const float* cprev = c_tm1 + mbase;
    float* hout0 = out;
    float* hout1 = out + (size_t)MODELS * BATCH * UNITS;
    float* cout = out + 2 * (size_t)MODELS * BATCH * UNITS;

    const int rowoff = kq * 4;
#pragma unroll
    for (int mr = 0; mr < 2; ++mr) {
#pragma unroll
        for (int r = 0; r < 4; ++r) {
            const int b = b0 + mr * 16 + rowoff + r;
            const float z0 = acc[mr][0][r] + bi;
            const float z1 = acc[mr][1][r] + bff;
            const float z2 = acc[mr][2][r] + bcc;
            const float z3 = acc[mr][3][r] + bo;
            const float ig = sigmoidf_(z0);
            const float fg = sigmoidf_(z1);
            const float cand = tanhf_(z2);
            const float og = sigmoidf_(z3);
            const size_t idx = (size_t)b * UNITS + bcol;
            const float c = fg * cprev[idx] + ig * cand;
            const float hh = og * tanhf_(c);
            hout0[mbase + idx] = hh;
            hout1[mbase + idx] = hh;
            cout[mbase + idx] = c;
        }
    }
}

extern "C" void kernel_launch(void* const* d_in, const int* in_sizes, int n_in,
                              void* d_out, int out_size, void* d_ws, size_t ws_size,
                              hipStream_t stream) {
    const float* inputs = (const float*)d_in[0];
    const float* h_tm1 = (const float*)d_in[1];
    const float* c_tm1 = (const float*)d_in[2];
    const float* kernel = (const float*)d_in[3];
    const float* rkernel = (const float*)d_in[4];
    const float* bias = (const float*)d_in[5];
    float* out = (float*)d_out;

    const size_t need = (size_t)2 * GRAN_PER_TENSOR * sizeof(short8);  // 8 MB
    if (ws_size >= need) {
        short8* P = (short8*)d_ws;
        hipLaunchKernelGGL(prepack_A_kernel, dim3(2 * GRAN_PER_TENSOR / 256), dim3(256),
                           0, stream, inputs, h_tm1, P);
        hipLaunchKernelGGL((lstm_main_kernel<true>), dim3(MODELS * 16), dim3(256), 0, stream,
                           inputs, h_tm1, c_tm1, kernel, rkernel, bias, P, out);
    } else {
        hipLaunchKernelGGL((lstm_main_kernel<false>), dim3(MODELS * 16), dim3(256), 0, stream,
                           inputs, h_tm1, c_tm1, kernel, rkernel, bias, nullptr, out);
    }
}

// Round 4
// 135.171 us; speedup vs baseline: 1.7742x; 1.4419x over previous
//
#include <hip/hip_runtime.h>
#include <hip/hip_bf16.h>

#define MODELS 64
#define BATCH 64
#define IN_DIM 512
#define UNITS 512
#define NCOLS 2048
// Packed-A: per tensor [m][ks16][kg4][row64] granules of 8 bf16 (16 B)
#define GRAN_PER_TENSOR (MODELS * 16 * 4 * 64)  // 262144 granules = 4 MB/tensor

typedef __attribute__((ext_vector_type(8))) short short8;
typedef __attribute__((ext_vector_type(4))) float f32x4;

static __device__ __forceinline__ short f2bf(float f) {
    return __builtin_bit_cast(short, __float2bfloat16(f));
}
static __device__ __forceinline__ float sigmoidf_(float x) {
    return 1.0f / (1.0f + __expf(-x));
}
static __device__ __forceinline__ float tanhf_(float x) {
    float e = __expf(-2.0f * fabsf(x));
    float r = (1.0f - e) / (1.0f + e);
    return copysignf(r, x);
}

// Re-layout inputs & h_tm1 (f32) into bf16 MFMA-A-fragment order.
__global__ __launch_bounds__(256) void prepack_A_kernel(
    const float* __restrict__ x, const float* __restrict__ h,
    short8* __restrict__ P)
{
    const int t = blockIdx.x * 256 + threadIdx.x;   // [0, 2*262144)
    const int tensor = t >> 18;
    const int r = t & (GRAN_PER_TENSOR - 1);
    const int kg = r & 3;
    const int row = (r >> 2) & 63;
    const int ks = (r >> 8) & 15;
    const int m = r >> 12;
    const float* src = (tensor ? h : x) + ((size_t)(m * 64 + row) * 512 + ks * 32 + kg * 8);
    f32x4 a0 = *(const f32x4*)src;
    f32x4 a1 = *(const f32x4*)(src + 4);
    short8 v;
    v[0] = f2bf(a0[0]); v[1] = f2bf(a0[1]); v[2] = f2bf(a0[2]); v[3] = f2bf(a0[3]);
    v[4] = f2bf(a1[0]); v[5] = f2bf(a1[1]); v[6] = f2bf(a1[2]); v[7] = f2bf(a1[3]);
    P[(size_t)tensor * GRAN_PER_TENSOR + (size_t)((m * 16 + ks) * 4 + kg) * 64 + row] = v;
}

// 512 blocks (model x 64-unit tile) x 512 threads (8 waves).
// LDS: two 32KB stage buffers (weights, f32 [32k][256c]); reused as z[64][256] f32.
// Wave w owns packed col-tiles {2w, 2w+1}; full 64-batch via acc[4][2].
__global__ __launch_bounds__(512, 4) void lstm_main_kernel(
    const float* __restrict__ c_tm1,
    const float* __restrict__ kernel_,
    const float* __restrict__ rkernel,
    const float* __restrict__ bias,
    const short8* __restrict__ Pa,
    float* __restrict__ out)
{
    __shared__ float lds[16384];  // 64 KB

    const int bid = blockIdx.x;
    const int m = bid >> 3;
    const int u0 = (bid & 7) * 64;
    const int tid = threadIdx.x;
    const int wave = tid >> 6;
    const int lane = tid & 63;
    const int col16 = lane & 15;
    const int kq = lane >> 4;

    // staging: lane l covers packed cols 4l..4l+3 of a k-row
    // packed c = gate*64 + uloc  <->  global col = gate*512 + u0 + uloc
    const int wcol = kq * 512 + u0 + col16 * 4;  // (l>>4)*512 + u0 + (l&15)*4

    const float* wbase[2] = { kernel_ + (size_t)m * IN_DIM * NCOLS,
                              rkernel + (size_t)m * UNITS * NCOLS };
    const short8* pabase[2] = { Pa + (size_t)m * 4096,
                                Pa + GRAN_PER_TENSOR + (size_t)m * 4096 };

    f32x4 acc[4][2];
#pragma unroll
    for (int bt = 0; bt < 4; ++bt)
#pragma unroll
        for (int c = 0; c < 2; ++c) acc[bt][c] = (f32x4){0.f, 0.f, 0.f, 0.f};

    // ---- stage one 32-k-row K-step of weights into LDS buffer `bufsel` ----
    auto STAGE = [&](int step, int bufsel) {
        const float* wb = wbase[step >> 4];
        const int krow0 = (step & 15) * 32;
#pragma unroll
        for (int j = 0; j < 4; ++j) {
            const int k = j * 8 + wave;                 // rows {w, w+8, w+16, w+24}
            const float* src = wb + (size_t)(krow0 + k) * NCOLS + wcol;
            float* dst = lds + bufsel * 8192 + k * 256; // wave-uniform, linear per lane
            __builtin_amdgcn_global_load_lds(
                (const __attribute__((address_space(1))) void*)src,
                (__attribute__((address_space(3))) void*)dst, 16, 0, 0);
        }
    };

    // prologue
    STAGE(0, 0);

    short8 af[4];
    for (int t = 0; t < 32; ++t) {
        const int cur = t & 1;
        // ---- A fragments for step t (asm: exact vmcnt bookkeeping) ----
        {
            const short8* pb = pabase[t >> 4] + (size_t)((t & 15) * 4 + kq) * 64 + col16;
#pragma unroll
            for (int bt = 0; bt < 4; ++bt) {
                asm volatile("global_load_dwordx4 %0, %1, off"
                             : "=v"(af[bt]) : "v"(pb + bt * 16) : "memory");
            }
        }
        if (t < 31) {
            STAGE(t + 1, cur ^ 1);
            // queue: [stage_t(4) | A_t(4) | stage_{t+1}(4)] -> leave only stage_{t+1}
            asm volatile("s_waitcnt vmcnt(4)"
                         : "+v"(af[0]), "+v"(af[1]), "+v"(af[2]), "+v"(af[3]) :: "memory");
        } else {
            asm volatile("s_waitcnt vmcnt(0)"
                         : "+v"(af[0]), "+v"(af[1]), "+v"(af[2]), "+v"(af[3]) :: "memory");
        }
        asm volatile("s_barrier" ::: "memory");

        // ---- compute step t from buf[cur] ----
        {
            const float* lb = lds + cur * 8192;
#pragma unroll
            for (int c = 0; c < 2; ++c) {
                const int cb = (wave * 2 + c) * 16 + col16;
                short8 bfr;
#pragma unroll
                for (int i = 0; i < 8; ++i)
                    bfr[i] = f2bf(lb[(kq * 8 + i) * 256 + cb]);
#pragma unroll
                for (int bt = 0; bt < 4; ++bt)
                    acc[bt][c] = __builtin_amdgcn_mfma_f32_16x16x32_bf16(
                        af[bt], bfr, acc[bt][c], 0, 0, 0);
            }
        }
        asm volatile("s_waitcnt lgkmcnt(0)" ::: "memory");
        asm volatile("s_barrier" ::: "memory");
    }

    // ---- z exchange through LDS (buffers are free now) ----
#pragma unroll
    for (int bt = 0; bt < 4; ++bt)
#pragma unroll
        for (int c = 0; c < 2; ++c)
#pragma unroll
            for (int r = 0; r < 4; ++r)
                lds[(size_t)(bt * 16 + kq * 4 + r) * 256 + (wave * 2 + c) * 16 + col16] =
                    acc[bt][c][r];
    __syncthreads();

    // ---- fused gate epilogue: thread -> (batch b, 8 units) ----
    const int b = tid >> 3;
    const int ug = (tid & 7) * 8;

    float zi[8], zf[8], zc[8], zo[8];
    *(f32x4*)&zi[0] = *(const f32x4*)&lds[b * 256 + 0 + ug];
    *(f32x4*)&zi[4] = *(const f32x4*)&lds[b * 256 + 0 + ug + 4];
    *(f32x4*)&zf[0] = *(const f32x4*)&lds[b * 256 + 64 + ug];
    *(f32x4*)&zf[4] = *(const f32x4*)&lds[b * 256 + 64 + ug + 4];
    *(f32x4*)&zc[0] = *(const f32x4*)&lds[b * 256 + 128 + ug];
    *(f32x4*)&zc[4] = *(const f32x4*)&lds[b * 256 + 128 + ug + 4];
    *(f32x4*)&zo[0] = *(const f32x4*)&lds[b * 256 + 192 + ug];
    *(f32x4*)&zo[4] = *(const f32x4*)&lds[b * 256 + 192 + ug + 4];

    const float* bb = bias + (size_t)m * NCOLS;
    float bi[8], bf_[8], bc[8], bo[8];
    *(f32x4*)&bi[0] = *(const f32x4*)&bb[0 * 512 + u0 + ug];
    *(f32x4*)&bi[4] = *(const f32x4*)&bb[0 * 512 + u0 + ug + 4];
    *(f32x4*)&bf_[0] = *(const f32x4*)&bb[1 * 512 + u0 + ug];
    *(f32x4*)&bf_[4] = *(const f32x4*)&bb[1 * 512 + u0 + ug + 4];
    *(f32x4*)&bc[0] = *(const f32x4*)&bb[2 * 512 + u0 + ug];
    *(f32x4*)&bc[4] = *(const f32x4*)&bb[2 * 512 + u0 + ug + 4];
    *(f32x4*)&bo[0] = *(const f32x4*)&bb[3 * 512 + u0 + ug];
    *(f32x4*)&bo[4] = *(const f32x4*)&bb[3 * 512 + u0 + ug + 4];

    const size_t cidx = (size_t)m * (BATCH * UNITS) + (size_t)b * UNITS + u0 + ug;
    float cp[8];
    *(f32x4*)&cp[0] = *(const f32x4*)&c_tm1[cidx];
    *(f32x4*)&cp[4] = *(const f32x4*)&c_tm1[cidx + 4];

    float hv[8], cv[8];
#pragma unroll
    for (int j = 0; j < 8; ++j) {
        const float ig = sigmoidf_(zi[j] + bi[j]);
        const float fg = sigmoidf_(zf[j] + bf_[j]);
        const float cand = tanhf_(zc[j] + bc[j]);
        const float og = sigmoidf_(zo[j] + bo[j]);
        const float c = fg * cp[j] + ig * cand;
        cv[j] = c;
        hv[j] = og * tanhf_(c);
    }

    float* hout0 = out;
    float* hout1 = out + (size_t)MODELS * BATCH * UNITS;
    float* cout = out + 2 * (size_t)MODELS * BATCH * UNITS;
    *(f32x4*)&hout0[cidx] = *(const f32x4*)&hv[0];
    *(f32x4*)&hout0[cidx + 4] = *(const f32x4*)&hv[4];
    *(f32x4*)&hout1[cidx] = *(const f32x4*)&hv[0];
    *(f32x4*)&hout1[cidx + 4] = *(const f32x4*)&hv[4];
    *(f32x4*)&cout[cidx] = *(const f32x4*)&cv[0];
    *(f32x4*)&cout[cidx + 4] = *(const f32x4*)&cv[4];
}

extern "C" void kernel_launch(void* const* d_in, const int* in_sizes, int n_in,
                              void* d_out, int out_size, void* d_ws, size_t ws_size,
                              hipStream_t stream) {
    const float* inputs = (const float*)d_in[0];
    const float* h_tm1 = (const float*)d_in[1];
    const float* c_tm1 = (const float*)d_in[2];
    const float* kernel_ = (const float*)d_in[3];
    const float* rkernel = (const float*)d_in[4];
    const float* bias = (const float*)d_in[5];
    float* out = (float*)d_out;

    short8* P = (short8*)d_ws;  // needs 8 MB; ws is ample (validated in rounds 2-3)
    hipLaunchKernelGGL(prepack_A_kernel, dim3(2 * GRAN_PER_TENSOR / 256), dim3(256),
                       0, stream, inputs, h_tm1, P);
    hipLaunchKernelGGL(lstm_main_kernel, dim3(MODELS * 8), dim3(512), 0, stream,
                       c_tm1, kernel_, rkernel, bias, P, out);
}